// Round 5
// baseline (909.074 us; speedup 1.0000x reference)
//
#include <hip/hip_runtime.h>
#include <math.h>

// ---------------------------------------------------------------------------
// GraphAttentionEmbedding (TGN TransformerConv, H=2, C=64, D=128, EDGE_DIM=256)
//   CSR build: hist -> scan -> fill (fill also emits src_perm, rel_perm)
//   K1 k_node_mfma x2: [q|k] then [v|skip] via bf16 MFMA, 64 KB W^T in LDS
//   K2 k_edge_mfma: e[slot] = [cos(rel)|msg[perm[slot]]] @ We, CSR-slot order
//                   msg loads hoisted to tile start (latency hidden by cos half)
//   K3 k_agg: wave per dst, src indices preloaded+shfl-broadcast, 2 edges/iter
// ---------------------------------------------------------------------------

#define SCALE_ATTN 0.125f
#define SCAN_CHUNK 512

typedef __attribute__((ext_vector_type(8))) short bf16x8;
typedef __attribute__((ext_vector_type(4))) float f32x4;

union AFrag { bf16x8 v; unsigned short u[8]; };

__device__ __forceinline__ unsigned short f2bf(float f) {
    unsigned int u = __float_as_uint(f);
    u += 0x7fffu + ((u >> 16) & 1u);          // RNE
    return (unsigned short)(u >> 16);
}
__device__ __forceinline__ float bf2f(unsigned int lo16) {
    return __uint_as_float(lo16 << 16);
}
__device__ __forceinline__ float4 unpack4(uint2 u) {
    return make_float4(bf2f(u.x & 0xffffu), bf2f(u.x >> 16),
                       bf2f(u.y & 0xffffu), bf2f(u.y >> 16));
}

// ---------------------------------------------------------------------------
// K1: node linears via MFMA, one 256-col pair per launch.
// LDS: W^T bf16 [n=256][k=128] swizzled (64 KB). 512 thr = 8 waves,
// tile = 128 nodes. cols 0..127 -> o0 (bf16); 128..255 -> of1 ? f32 : o1.
// ---------------------------------------------------------------------------
__global__ __launch_bounds__(512, 4) void k_node_mfma(
    const float4* __restrict__ x4,
    const float* __restrict__ W0, const float* __restrict__ W1,
    const float* __restrict__ b0, const float* __restrict__ b1,
    unsigned short* __restrict__ o0, unsigned short* __restrict__ o1,
    float* __restrict__ of1,
    int N, int numTiles)
{
    __shared__ __align__(16) unsigned short sW[256 * 128];   // 64 KB
    const int tid = threadIdx.x;
    const int w = tid >> 6, l = tid & 63;
    const int l15 = l & 15, lg = l >> 4;

    for (int c = tid; c < 4096; c += 512) {
        const int n = c >> 4, k0 = (c & 15) << 3;
        const float* Wsrc = (n < 128) ? W0 : W1;
        const int col = n & 127;
        AFrag af;
        #pragma unroll
        for (int j = 0; j < 8; ++j) af.u[j] = f2bf(Wsrc[(k0 + j) * 128 + col]);
        const int byteoff = ((n << 8) + (k0 << 1)) ^ ((n & 7) << 4);
        *(bf16x8*)((char*)sW + byteoff) = af.v;
    }
    __syncthreads();

    for (int tile = blockIdx.x; tile < numTiles; tile += gridDim.x) {
        const int arow = tile * 128 + w * 16 + l15;
        const int na = min(arow, N - 1);

        f32x4 acc[16];
        #pragma unroll
        for (int i = 0; i < 16; ++i) acc[i] = (f32x4)(0.f);

        #pragma unroll 2
        for (int kk = 0; kk < 4; ++kk) {
            const int kbase = (kk << 5) + (lg << 3);
            const float4 x0 = x4[(size_t)na * 32 + (kbase >> 2)];
            const float4 x1 = x4[(size_t)na * 32 + (kbase >> 2) + 1];
            AFrag a;
            a.u[0] = f2bf(x0.x); a.u[1] = f2bf(x0.y);
            a.u[2] = f2bf(x0.z); a.u[3] = f2bf(x0.w);
            a.u[4] = f2bf(x1.x); a.u[5] = f2bf(x1.y);
            a.u[6] = f2bf(x1.z); a.u[7] = f2bf(x1.w);
            const int bbase = ((l15 << 8) + (kbase << 1)) ^ ((l & 7) << 4);
            #pragma unroll
            for (int nt = 0; nt < 16; ++nt) {
                const bf16x8 b = *(const bf16x8*)((const char*)sW + (bbase + (nt << 12)));
                acc[nt] = __builtin_amdgcn_mfma_f32_16x16x32_bf16(a.v, b, acc[nt], 0, 0, 0);
            }
        }

        const int drow0 = tile * 128 + w * 16 + (lg << 2);
        #pragma unroll
        for (int nt = 0; nt < 16; ++nt) {
            const int col = (nt << 4) + l15;        // 0..255
            const int c128 = col & 127;
            const float bias = (col < 128) ? b0[c128] : b1[c128];
            #pragma unroll
            for (int r = 0; r < 4; ++r) {
                const int node = drow0 + r;
                if (node < N) {
                    const float val = acc[nt][r] + bias;
                    if (col < 128)   o0[(size_t)node * 128 + c128] = f2bf(val);
                    else if (of1)    of1[(size_t)node * 128 + c128] = val;
                    else             o1[(size_t)node * 128 + c128] = f2bf(val);
                }
            }
        }
    }
}

// ---------------------------------------------------------------------------
// K2: edge GEMM via MFMA, CSR-slot order. LDS: We^T bf16 [n=128][k=256]
// swizzled (64 KB). 512 thr = 8 waves, tile = 128 slots, 16 slots/wave.
// msg loads for the whole tile hoisted BEFORE the cos half (latency hiding).
// ---------------------------------------------------------------------------
__global__ __launch_bounds__(512, 4) void k_edge_mfma(
    const float4* __restrict__ msg4,
    const int* __restrict__ perm, const float* __restrict__ relp,
    const float4* __restrict__ tw4, const float4* __restrict__ tb4,
    const float* __restrict__ We,
    unsigned short* __restrict__ ebuf, int E, int numTiles)
{
    __shared__ __align__(16) unsigned short sWe[128 * 256];   // 64 KB
    const int tid = threadIdx.x;
    const int w = tid >> 6, l = tid & 63;
    const int l15 = l & 15, lg = l >> 4;

    for (int c = tid; c < 4096; c += 512) {
        const int n = c >> 5, k0 = (c & 31) << 3;
        AFrag af;
        #pragma unroll
        for (int j = 0; j < 8; ++j) af.u[j] = f2bf(We[(k0 + j) * 128 + n]);
        const int byteoff = ((n << 9) + (k0 << 1)) ^ ((n & 7) << 4);
        *(bf16x8*)((char*)sWe + byteoff) = af.v;
    }
    __syncthreads();

    for (int tile = blockIdx.x; tile < numTiles; tile += gridDim.x) {
        const int slot = tile * 128 + w * 16 + l15;
        const int sa = min(slot, E - 1);
        const int eid = perm[sa];
        const float rel = relp[sa];

        // ---- hoisted msg prefetch: 8 independent 16 B loads, one random row
        float4 mf[8];
        #pragma unroll
        for (int kk = 0; kk < 4; ++kk) {
            const int fi = (kk << 3) + (lg << 1);
            mf[kk * 2]     = msg4[(size_t)eid * 32 + fi];
            mf[kk * 2 + 1] = msg4[(size_t)eid * 32 + fi + 1];
        }

        f32x4 acc[8];
        #pragma unroll
        for (int i = 0; i < 8; ++i) acc[i] = (f32x4)(0.f);

        // k = 0..127: time-encoding half (covers msg load latency)
        #pragma unroll
        for (int kk = 0; kk < 4; ++kk) {
            const int kbase = (kk << 5) + (lg << 3);
            const float4 tww = tw4[kbase >> 2];
            const float4 tw2 = tw4[(kbase >> 2) + 1];
            const float4 tbb = tb4[kbase >> 2];
            const float4 tb2 = tb4[(kbase >> 2) + 1];
            AFrag a;
            a.u[0] = f2bf(__cosf(fmaf(rel, tww.x, tbb.x)));
            a.u[1] = f2bf(__cosf(fmaf(rel, tww.y, tbb.y)));
            a.u[2] = f2bf(__cosf(fmaf(rel, tww.z, tbb.z)));
            a.u[3] = f2bf(__cosf(fmaf(rel, tww.w, tbb.w)));
            a.u[4] = f2bf(__cosf(fmaf(rel, tw2.x, tb2.x)));
            a.u[5] = f2bf(__cosf(fmaf(rel, tw2.y, tb2.y)));
            a.u[6] = f2bf(__cosf(fmaf(rel, tw2.z, tb2.z)));
            a.u[7] = f2bf(__cosf(fmaf(rel, tw2.w, tb2.w)));
            const int bbase = ((l15 << 9) + (kbase << 1)) ^ ((l & 7) << 4);
            #pragma unroll
            for (int nt = 0; nt < 8; ++nt) {
                const bf16x8 b = *(const bf16x8*)((const char*)sWe + (bbase + (nt << 13)));
                acc[nt] = __builtin_amdgcn_mfma_f32_16x16x32_bf16(a.v, b, acc[nt], 0, 0, 0);
            }
        }
        // k = 128..255: msg half from prefetched registers
        #pragma unroll
        for (int kk = 0; kk < 4; ++kk) {
            const int km = (kk << 5) + (lg << 3);
            const float4 m0 = mf[kk * 2];
            const float4 m1 = mf[kk * 2 + 1];
            AFrag a;
            a.u[0] = f2bf(m0.x); a.u[1] = f2bf(m0.y);
            a.u[2] = f2bf(m0.z); a.u[3] = f2bf(m0.w);
            a.u[4] = f2bf(m1.x); a.u[5] = f2bf(m1.y);
            a.u[6] = f2bf(m1.z); a.u[7] = f2bf(m1.w);
            const int bbase = ((l15 << 9) + ((128 + km) << 1)) ^ ((l & 7) << 4);
            #pragma unroll
            for (int nt = 0; nt < 8; ++nt) {
                const bf16x8 b = *(const bf16x8*)((const char*)sWe + (bbase + (nt << 13)));
                acc[nt] = __builtin_amdgcn_mfma_f32_16x16x32_bf16(a.v, b, acc[nt], 0, 0, 0);
            }
        }
        // epilogue: store e (bf16) at CSR slot rows
        const int drow0 = tile * 128 + w * 16 + (lg << 2);
        #pragma unroll
        for (int nt = 0; nt < 8; ++nt) {
            const int col = (nt << 4) + l15;
            #pragma unroll
            for (int r = 0; r < 4; ++r) {
                const int erow = drow0 + r;
                if (erow < E) ebuf[(size_t)erow * 128 + col] = f2bf(acc[nt][r]);
            }
        }
    }
}

// ---------------------------------------------------------------------------
// CSR build
// ---------------------------------------------------------------------------
__global__ __launch_bounds__(256) void k_hist(
    const int* __restrict__ ei, int* __restrict__ counts, int E)
{
    int i = blockIdx.x * 256 + threadIdx.x;
    if (i < E) atomicAdd(&counts[ei[E + i]], 1);
}

__global__ __launch_bounds__(256) void k_scan_partial(
    const int* __restrict__ counts, int* __restrict__ partial, int N)
{
    const int base = blockIdx.x * SCAN_CHUNK;
    int v = 0;
    for (int i = threadIdx.x; i < SCAN_CHUNK; i += 256) {
        const int idx = base + i;
        if (idx < N) v += counts[idx];
    }
    __shared__ int red[4];
    #pragma unroll
    for (int off = 1; off < 64; off <<= 1) v += __shfl_xor(v, off);
    if ((threadIdx.x & 63) == 0) red[threadIdx.x >> 6] = v;
    __syncthreads();
    if (threadIdx.x == 0) partial[blockIdx.x] = red[0] + red[1] + red[2] + red[3];
}

__global__ __launch_bounds__(256) void k_scan_base(
    const int* __restrict__ partial, int* __restrict__ base, int nb)
{
    __shared__ int tmp[256];
    const int v = (threadIdx.x < nb) ? partial[threadIdx.x] : 0;
    tmp[threadIdx.x] = v;
    __syncthreads();
    for (int off = 1; off < 256; off <<= 1) {
        const int add = (threadIdx.x >= off) ? tmp[threadIdx.x - off] : 0;
        __syncthreads();
        tmp[threadIdx.x] += add;
        __syncthreads();
    }
    if (threadIdx.x < nb) base[threadIdx.x] = tmp[threadIdx.x] - v;
}

__global__ __launch_bounds__(256) void k_scan_final(
    const int* __restrict__ counts, const int* __restrict__ base,
    int* __restrict__ rowptr, int* __restrict__ cursor, int N)
{
    const int i0 = blockIdx.x * SCAN_CHUNK;
    __shared__ int tmp[256];
    const int ia = i0 + threadIdx.x * 2, ib = ia + 1;
    const int v0 = (ia < N) ? counts[ia] : 0;
    const int v1 = (ib < N) ? counts[ib] : 0;
    const int s = v0 + v1;
    tmp[threadIdx.x] = s;
    __syncthreads();
    for (int off = 1; off < 256; off <<= 1) {
        const int add = (threadIdx.x >= off) ? tmp[threadIdx.x - off] : 0;
        __syncthreads();
        tmp[threadIdx.x] += add;
        __syncthreads();
    }
    const int excl = tmp[threadIdx.x] - s + base[blockIdx.x];
    if (ia < N) { rowptr[ia] = excl;      cursor[ia] = excl; }
    if (ib < N) { rowptr[ib] = excl + v0; cursor[ib] = excl + v0; }
}

// fill: permutation + src gather + rel_t, all emitted in CSR-slot order
__global__ __launch_bounds__(256) void k_fill(
    const int* __restrict__ ei, const float* __restrict__ t,
    const float* __restrict__ lu, int* __restrict__ cursor,
    int* __restrict__ perm, int* __restrict__ srcp,
    float* __restrict__ relp, int E)
{
    int i = blockIdx.x * 256 + threadIdx.x;
    if (i < E) {
        const int s = ei[i];
        const int d = ei[E + i];
        const int pos = atomicAdd(&cursor[d], 1);
        perm[pos] = i;
        srcp[pos] = s;
        relp[pos] = t[i] - lu[s];
    }
}

// ---------------------------------------------------------------------------
// K3: fused aggregation. One wave per dst. src indices preloaded into one
// register per lane (coalesced), broadcast via shfl -> single memory level
// per iteration; 2 edges/iter (e2 = l>>5), iterations independent (ILP).
// ---------------------------------------------------------------------------
__global__ __launch_bounds__(256) void k_agg(
    const int* __restrict__ srcp,
    const int* __restrict__ rowptr, const int* __restrict__ counts,
    const uint2* __restrict__ qb2, const uint2* __restrict__ kb2,
    const uint2* __restrict__ vb2, const uint2* __restrict__ eb2,
    float4* __restrict__ out4, int N)
{
    const int d = blockIdx.x * 4 + (threadIdx.x >> 6);
    if (d >= N) return;
    const int l = threadIdx.x & 63;
    const int u32 = l & 31;
    const int e2 = l >> 5;
    const int start = rowptr[d];
    const int deg = counts[d];

    const float4 qv = unpack4(qb2[(size_t)d * 32 + u32]);
    float4 acc = make_float4(0.f, 0.f, 0.f, 0.f);
    float denom = 0.f;

    for (int cbase = 0; cbase < deg; cbase += 64) {
        const int clen = min(deg - cbase, 64);
        int mySrc = 0;
        if (l < clen) mySrc = srcp[start + cbase + l];    // one coalesced load

        #pragma unroll 2
        for (int i = 0; i < clen; i += 2) {
            const int off = i + e2;
            const bool valid = off < clen;
            const int offc = valid ? off : 0;
            const int src = __shfl(mySrc, offc);
            const int ss = start + cbase + offc;
            const float4 kv = unpack4(kb2[(size_t)src * 32 + u32]);
            const float4 ev = unpack4(eb2[(size_t)ss * 32 + u32]);
            const float4 vv = unpack4(vb2[(size_t)src * 32 + u32]);
            float s = qv.x * (kv.x + ev.x) + qv.y * (kv.y + ev.y) +
                      qv.z * (kv.z + ev.z) + qv.w * (kv.w + ev.w);
            s += __shfl_xor(s, 1);
            s += __shfl_xor(s, 2);
            s += __shfl_xor(s, 4);
            s += __shfl_xor(s, 8);
            const float p = valid ? __expf(s * SCALE_ATTN) : 0.f;
            denom += p;
            acc.x = fmaf(p, vv.x + ev.x, acc.x);
            acc.y = fmaf(p, vv.y + ev.y, acc.y);
            acc.z = fmaf(p, vv.z + ev.z, acc.z);
            acc.w = fmaf(p, vv.w + ev.w, acc.w);
        }
    }
    acc.x += __shfl_xor(acc.x, 32);
    acc.y += __shfl_xor(acc.y, 32);
    acc.z += __shfl_xor(acc.z, 32);
    acc.w += __shfl_xor(acc.w, 32);
    denom += __shfl_xor(denom, 32);

    if (l < 32) {
        const float inv = 1.f / (denom + 1e-16f);
        float4* o = out4 + (size_t)d * 32 + u32;
        const float4 cur = *o;                    // skip (from k_node v|skip pass)
        *o = make_float4(fmaf(acc.x, inv, cur.x), fmaf(acc.y, inv, cur.y),
                         fmaf(acc.z, inv, cur.z), fmaf(acc.w, inv, cur.w));
    }
}

// ---------------------------------------------------------------------------
extern "C" void kernel_launch(void* const* d_in, const int* in_sizes, int n_in,
                              void* d_out, int out_size, void* d_ws, size_t ws_size,
                              hipStream_t stream)
{
    const float* x   = (const float*)d_in[0];
    const float* lu  = (const float*)d_in[1];
    const int*   ei  = (const int*)d_in[2];
    const float* t   = (const float*)d_in[3];
    const float* msg = (const float*)d_in[4];
    const float* tw  = (const float*)d_in[5];
    const float* tb  = (const float*)d_in[6];
    const float* Wq  = (const float*)d_in[7];
    const float* bq  = (const float*)d_in[8];
    const float* Wk  = (const float*)d_in[9];
    const float* bk  = (const float*)d_in[10];
    const float* Wv  = (const float*)d_in[11];
    const float* bv  = (const float*)d_in[12];
    const float* We  = (const float*)d_in[13];
    const float* Wsk = (const float*)d_in[14];
    const float* bsk = (const float*)d_in[15];

    const int N = in_sizes[1];   // last_update: N elements
    const int E = in_sizes[3];   // t: E elements
    float* out = (float*)d_out;

    char* ws = (char*)d_ws;
    unsigned short* qb = (unsigned short*)ws;  ws += (size_t)N * 128 * sizeof(unsigned short);
    unsigned short* kb = (unsigned short*)ws;  ws += (size_t)N * 128 * sizeof(unsigned short);
    unsigned short* vb = (unsigned short*)ws;  ws += (size_t)N * 128 * sizeof(unsigned short);
    unsigned short* eb = (unsigned short*)ws;  ws += (size_t)E * 128 * sizeof(unsigned short);
    int*   counts  = (int*)ws;   ws += (size_t)N * sizeof(int);
    int*   rowptr  = (int*)ws;   ws += (size_t)N * sizeof(int);
    int*   cursor  = (int*)ws;   ws += (size_t)N * sizeof(int);
    int*   perm    = (int*)ws;   ws += (size_t)E * sizeof(int);
    int*   srcp    = (int*)ws;   ws += (size_t)E * sizeof(int);
    float* relp    = (float*)ws; ws += (size_t)E * sizeof(float);
    int*   partial = (int*)ws;   ws += 512 * sizeof(int);
    int*   baseArr = (int*)ws;   ws += 512 * sizeof(int);

    const int nScan = (N + SCAN_CHUNK - 1) / SCAN_CHUNK;

    hipMemsetAsync(counts, 0, (size_t)N * sizeof(int), stream);

    // CSR build first (k_edge needs fill output)
    k_hist<<<(E + 255) / 256, 256, 0, stream>>>(ei, counts, E);
    k_scan_partial<<<nScan, 256, 0, stream>>>(counts, partial, N);
    k_scan_base<<<1, 256, 0, stream>>>(partial, baseArr, nScan);
    k_scan_final<<<nScan, 256, 0, stream>>>(counts, baseArr, rowptr, cursor, N);
    k_fill<<<(E + 255) / 256, 256, 0, stream>>>(ei, t, lu, cursor, perm, srcp, relp, E);

    // node linears: [q|k] then [v|skip->d_out]
    const int nTN = (N + 127) / 128;
    k_node_mfma<<<min(nTN, 512), 512, 0, stream>>>(
        (const float4*)x, Wq, Wk, bq, bk, qb, kb, nullptr, N, nTN);
    k_node_mfma<<<min(nTN, 512), 512, 0, stream>>>(
        (const float4*)x, Wv, Wsk, bv, bsk, vb, nullptr, out, N, nTN);

    // edge GEMM in CSR-slot order
    const int nTE = (E + 127) / 128;
    k_edge_mfma<<<min(nTE, 1024), 512, 0, stream>>>(
        (const float4*)msg, perm, relp,
        (const float4*)tw, (const float4*)tb, We, eb, E, nTE);

    // fused aggregation (sequential e/src streams, no atomics)
    k_agg<<<(N + 3) / 4, 256, 0, stream>>>(
        srcp, rowptr, counts,
        (const uint2*)qb, (const uint2*)kb, (const uint2*)vb, (const uint2*)eb,
        (float4*)out, N);
}

// Round 7
// 422.100 us; speedup vs baseline: 2.1537x; 2.1537x over previous
//
#include <hip/hip_runtime.h>
#include <math.h>

// ---------------------------------------------------------------------------
// GraphAttentionEmbedding (TGN TransformerConv, H=2, C=64, D=128, EDGE_DIM=256)
//   CSR build: hist -> scan -> fill (perm: slot->edge, srcp: slot->src,
//              relo: rel_t in ORIGINAL edge order)
//   K1 k_node_mfma x2: [q|k] then [v|skip] via bf16 MFMA, 64 KB W^T in LDS
//   K2 k_edge_mfma: ORIGINAL edge order; all reads AND writes sequential
//                   (ebuf[edge]); coverage by construction (no rank scatter)
//   K3 k_agg: wave per dst; perm+srcp chunk-loaded coalesced, shfl-broadcast;
//             e-row gathered via perm (L3-resident); no atomics on output
// ---------------------------------------------------------------------------

#define SCALE_ATTN 0.125f
#define SCAN_CHUNK 512

typedef __attribute__((ext_vector_type(8))) short bf16x8;
typedef __attribute__((ext_vector_type(4))) float f32x4;

union AFrag { bf16x8 v; unsigned short u[8]; };

__device__ __forceinline__ unsigned short f2bf(float f) {
    unsigned int u = __float_as_uint(f);
    u += 0x7fffu + ((u >> 16) & 1u);          // RNE
    return (unsigned short)(u >> 16);
}
__device__ __forceinline__ float bf2f(unsigned int lo16) {
    return __uint_as_float(lo16 << 16);
}
__device__ __forceinline__ float4 unpack4(uint2 u) {
    return make_float4(bf2f(u.x & 0xffffu), bf2f(u.x >> 16),
                       bf2f(u.y & 0xffffu), bf2f(u.y >> 16));
}

// ---------------------------------------------------------------------------
// K1: node linears via MFMA, one 256-col pair per launch.
// LDS: W^T bf16 [n=256][k=128] swizzled (64 KB). 512 thr = 8 waves,
// tile = 128 nodes. cols 0..127 -> o0 (bf16); 128..255 -> of1 ? f32 : o1.
// ---------------------------------------------------------------------------
__global__ __launch_bounds__(512, 4) void k_node_mfma(
    const float4* __restrict__ x4,
    const float* __restrict__ W0, const float* __restrict__ W1,
    const float* __restrict__ b0, const float* __restrict__ b1,
    unsigned short* __restrict__ o0, unsigned short* __restrict__ o1,
    float* __restrict__ of1,
    int N, int numTiles)
{
    __shared__ __align__(16) unsigned short sW[256 * 128];   // 64 KB
    const int tid = threadIdx.x;
    const int w = tid >> 6, l = tid & 63;
    const int l15 = l & 15, lg = l >> 4;

    for (int c = tid; c < 4096; c += 512) {
        const int n = c >> 4, k0 = (c & 15) << 3;
        const float* Wsrc = (n < 128) ? W0 : W1;
        const int col = n & 127;
        AFrag af;
        #pragma unroll
        for (int j = 0; j < 8; ++j) af.u[j] = f2bf(Wsrc[(k0 + j) * 128 + col]);
        const int byteoff = ((n << 8) + (k0 << 1)) ^ ((n & 7) << 4);
        *(bf16x8*)((char*)sW + byteoff) = af.v;
    }
    __syncthreads();

    for (int tile = blockIdx.x; tile < numTiles; tile += gridDim.x) {
        const int arow = tile * 128 + w * 16 + l15;
        const int na = min(arow, N - 1);

        f32x4 acc[16];
        #pragma unroll
        for (int i = 0; i < 16; ++i) acc[i] = (f32x4)(0.f);

        #pragma unroll 2
        for (int kk = 0; kk < 4; ++kk) {
            const int kbase = (kk << 5) + (lg << 3);
            const float4 x0 = x4[(size_t)na * 32 + (kbase >> 2)];
            const float4 x1 = x4[(size_t)na * 32 + (kbase >> 2) + 1];
            AFrag a;
            a.u[0] = f2bf(x0.x); a.u[1] = f2bf(x0.y);
            a.u[2] = f2bf(x0.z); a.u[3] = f2bf(x0.w);
            a.u[4] = f2bf(x1.x); a.u[5] = f2bf(x1.y);
            a.u[6] = f2bf(x1.z); a.u[7] = f2bf(x1.w);
            const int bbase = ((l15 << 8) + (kbase << 1)) ^ ((l & 7) << 4);
            #pragma unroll
            for (int nt = 0; nt < 16; ++nt) {
                const bf16x8 b = *(const bf16x8*)((const char*)sW + (bbase + (nt << 12)));
                acc[nt] = __builtin_amdgcn_mfma_f32_16x16x32_bf16(a.v, b, acc[nt], 0, 0, 0);
            }
        }

        const int drow0 = tile * 128 + w * 16 + (lg << 2);
        #pragma unroll
        for (int nt = 0; nt < 16; ++nt) {
            const int col = (nt << 4) + l15;        // 0..255
            const int c128 = col & 127;
            const float bias = (col < 128) ? b0[c128] : b1[c128];
            #pragma unroll
            for (int r = 0; r < 4; ++r) {
                const int node = drow0 + r;
                if (node < N) {
                    const float val = acc[nt][r] + bias;
                    if (col < 128)   o0[(size_t)node * 128 + c128] = f2bf(val);
                    else if (of1)    of1[(size_t)node * 128 + c128] = val;
                    else             o1[(size_t)node * 128 + c128] = f2bf(val);
                }
            }
        }
    }
}

// ---------------------------------------------------------------------------
// K2: edge GEMM via MFMA in ORIGINAL edge order. All reads sequential (relo,
// msg), all writes sequential (ebuf[edge]). LDS: We^T bf16 [n=128][k=256]
// swizzled (64 KB). 512 thr = 8 waves, tile = 128 edges, 16 edges/wave.
// Loads consumed immediately (no register spill).
// ---------------------------------------------------------------------------
__global__ __launch_bounds__(512, 4) void k_edge_mfma(
    const float4* __restrict__ msg4,
    const float* __restrict__ relo,
    const float4* __restrict__ tw4, const float4* __restrict__ tb4,
    const float* __restrict__ We,
    unsigned short* __restrict__ ebuf, int E, int numTiles)
{
    __shared__ __align__(16) unsigned short sWe[128 * 256];   // 64 KB
    const int tid = threadIdx.x;
    const int w = tid >> 6, l = tid & 63;
    const int l15 = l & 15, lg = l >> 4;

    for (int c = tid; c < 4096; c += 512) {
        const int n = c >> 5, k0 = (c & 31) << 3;
        AFrag af;
        #pragma unroll
        for (int j = 0; j < 8; ++j) af.u[j] = f2bf(We[(k0 + j) * 128 + n]);
        const int byteoff = ((n << 9) + (k0 << 1)) ^ ((n & 7) << 4);
        *(bf16x8*)((char*)sWe + byteoff) = af.v;
    }
    __syncthreads();

    for (int tile = blockIdx.x; tile < numTiles; tile += gridDim.x) {
        const int erow = tile * 128 + w * 16 + l15;
        const int sa = min(erow, E - 1);
        const float rel = relo[sa];                    // sequential

        f32x4 acc[8];
        #pragma unroll
        for (int i = 0; i < 8; ++i) acc[i] = (f32x4)(0.f);

        // k = 0..127: time-encoding half (pure compute)
        #pragma unroll 2
        for (int kk = 0; kk < 4; ++kk) {
            const int kbase = (kk << 5) + (lg << 3);
            const float4 tww = tw4[kbase >> 2];
            const float4 tw2 = tw4[(kbase >> 2) + 1];
            const float4 tbb = tb4[kbase >> 2];
            const float4 tb2 = tb4[(kbase >> 2) + 1];
            AFrag a;
            a.u[0] = f2bf(__cosf(fmaf(rel, tww.x, tbb.x)));
            a.u[1] = f2bf(__cosf(fmaf(rel, tww.y, tbb.y)));
            a.u[2] = f2bf(__cosf(fmaf(rel, tww.z, tbb.z)));
            a.u[3] = f2bf(__cosf(fmaf(rel, tww.w, tbb.w)));
            a.u[4] = f2bf(__cosf(fmaf(rel, tw2.x, tb2.x)));
            a.u[5] = f2bf(__cosf(fmaf(rel, tw2.y, tb2.y)));
            a.u[6] = f2bf(__cosf(fmaf(rel, tw2.z, tb2.z)));
            a.u[7] = f2bf(__cosf(fmaf(rel, tw2.w, tb2.w)));
            const int bbase = ((l15 << 9) + (kbase << 1)) ^ ((l & 7) << 4);
            #pragma unroll
            for (int nt = 0; nt < 8; ++nt) {
                const bf16x8 b = *(const bf16x8*)((const char*)sWe + (bbase + (nt << 13)));
                acc[nt] = __builtin_amdgcn_mfma_f32_16x16x32_bf16(a.v, b, acc[nt], 0, 0, 0);
            }
        }
        // k = 128..255: msg half, SEQUENTIAL rows, loads consumed immediately
        #pragma unroll 2
        for (int kk = 0; kk < 4; ++kk) {
            const int km = (kk << 5) + (lg << 3);
            const float4 m0 = msg4[(size_t)sa * 32 + (km >> 2)];
            const float4 m1 = msg4[(size_t)sa * 32 + (km >> 2) + 1];
            AFrag a;
            a.u[0] = f2bf(m0.x); a.u[1] = f2bf(m0.y);
            a.u[2] = f2bf(m0.z); a.u[3] = f2bf(m0.w);
            a.u[4] = f2bf(m1.x); a.u[5] = f2bf(m1.y);
            a.u[6] = f2bf(m1.z); a.u[7] = f2bf(m1.w);
            const int bbase = ((l15 << 9) + ((128 + km) << 1)) ^ ((l & 7) << 4);
            #pragma unroll
            for (int nt = 0; nt < 8; ++nt) {
                const bf16x8 b = *(const bf16x8*)((const char*)sWe + (bbase + (nt << 13)));
                acc[nt] = __builtin_amdgcn_mfma_f32_16x16x32_bf16(a.v, b, acc[nt], 0, 0, 0);
            }
        }
        // epilogue: sequential store at edge rows (coverage by construction)
        const int drow0 = tile * 128 + w * 16 + (lg << 2);
        #pragma unroll
        for (int nt = 0; nt < 8; ++nt) {
            const int col = (nt << 4) + l15;
            #pragma unroll
            for (int r = 0; r < 4; ++r) {
                const int er = drow0 + r;
                if (er < E) ebuf[(size_t)er * 128 + col] = f2bf(acc[nt][r]);
            }
        }
    }
}

// ---------------------------------------------------------------------------
// CSR build
// ---------------------------------------------------------------------------
__global__ __launch_bounds__(256) void k_hist(
    const int* __restrict__ ei, int* __restrict__ counts, int E)
{
    int i = blockIdx.x * 256 + threadIdx.x;
    if (i < E) atomicAdd(&counts[ei[E + i]], 1);
}

__global__ __launch_bounds__(256) void k_scan_partial(
    const int* __restrict__ counts, int* __restrict__ partial, int N)
{
    const int base = blockIdx.x * SCAN_CHUNK;
    int v = 0;
    for (int i = threadIdx.x; i < SCAN_CHUNK; i += 256) {
        const int idx = base + i;
        if (idx < N) v += counts[idx];
    }
    __shared__ int red[4];
    #pragma unroll
    for (int off = 1; off < 64; off <<= 1) v += __shfl_xor(v, off);
    if ((threadIdx.x & 63) == 0) red[threadIdx.x >> 6] = v;
    __syncthreads();
    if (threadIdx.x == 0) partial[blockIdx.x] = red[0] + red[1] + red[2] + red[3];
}

__global__ __launch_bounds__(256) void k_scan_base(
    const int* __restrict__ partial, int* __restrict__ base, int nb)
{
    __shared__ int tmp[256];
    const int v = (threadIdx.x < nb) ? partial[threadIdx.x] : 0;
    tmp[threadIdx.x] = v;
    __syncthreads();
    for (int off = 1; off < 256; off <<= 1) {
        const int add = (threadIdx.x >= off) ? tmp[threadIdx.x - off] : 0;
        __syncthreads();
        tmp[threadIdx.x] += add;
        __syncthreads();
    }
    if (threadIdx.x < nb) base[threadIdx.x] = tmp[threadIdx.x] - v;
}

__global__ __launch_bounds__(256) void k_scan_final(
    const int* __restrict__ counts, const int* __restrict__ base,
    int* __restrict__ rowptr, int* __restrict__ cursor, int N)
{
    const int i0 = blockIdx.x * SCAN_CHUNK;
    __shared__ int tmp[256];
    const int ia = i0 + threadIdx.x * 2, ib = ia + 1;
    const int v0 = (ia < N) ? counts[ia] : 0;
    const int v1 = (ib < N) ? counts[ib] : 0;
    const int s = v0 + v1;
    tmp[threadIdx.x] = s;
    __syncthreads();
    for (int off = 1; off < 256; off <<= 1) {
        const int add = (threadIdx.x >= off) ? tmp[threadIdx.x - off] : 0;
        __syncthreads();
        tmp[threadIdx.x] += add;
        __syncthreads();
    }
    const int excl = tmp[threadIdx.x] - s + base[blockIdx.x];
    if (ia < N) { rowptr[ia] = excl;      cursor[ia] = excl; }
    if (ib < N) { rowptr[ib] = excl + v0; cursor[ib] = excl + v0; }
}

// fill: perm (slot -> edge), srcp (slot -> src), relo (original edge order)
__global__ __launch_bounds__(256) void k_fill(
    const int* __restrict__ ei, const float* __restrict__ t,
    const float* __restrict__ lu, int* __restrict__ cursor,
    int* __restrict__ perm, int* __restrict__ srcp,
    float* __restrict__ relo, int E)
{
    int i = blockIdx.x * 256 + threadIdx.x;
    if (i < E) {
        const int s = ei[i];
        const int d = ei[E + i];
        const int pos = atomicAdd(&cursor[d], 1);
        perm[pos] = i;
        srcp[pos] = s;
        relo[i] = t[i] - lu[s];
    }
}

// ---------------------------------------------------------------------------
// K3: fused aggregation. One wave per dst. perm+srcp chunk-loaded coalesced
// into one register each, shfl-broadcast; 2 edges/iter (e2 = l>>5).
// e-rows gathered via perm (eb is L3-resident). One float4 store per lane.
// ---------------------------------------------------------------------------
__global__ __launch_bounds__(256) void k_agg(
    const int* __restrict__ srcp, const int* __restrict__ perm,
    const int* __restrict__ rowptr, const int* __restrict__ counts,
    const uint2* __restrict__ qb2, const uint2* __restrict__ kb2,
    const uint2* __restrict__ vb2, const uint2* __restrict__ eb2,
    float4* __restrict__ out4, int N)
{
    const int d = blockIdx.x * 4 + (threadIdx.x >> 6);
    if (d >= N) return;
    const int l = threadIdx.x & 63;
    const int u32 = l & 31;
    const int e2 = l >> 5;
    const int start = rowptr[d];
    const int deg = counts[d];

    const float4 qv = unpack4(qb2[(size_t)d * 32 + u32]);
    float4 acc = make_float4(0.f, 0.f, 0.f, 0.f);
    float denom = 0.f;

    for (int cbase = 0; cbase < deg; cbase += 64) {
        const int clen = min(deg - cbase, 64);
        int mySrc = 0, myEid = 0;
        if (l < clen) {
            mySrc = srcp[start + cbase + l];   // coalesced
            myEid = perm[start + cbase + l];   // coalesced
        }

        #pragma unroll 2
        for (int i = 0; i < clen; i += 2) {
            const int off = i + e2;
            const bool valid = off < clen;
            const int offc = valid ? off : 0;
            const int src = __shfl(mySrc, offc);
            const int eid = __shfl(myEid, offc);
            const float4 kv = unpack4(kb2[(size_t)src * 32 + u32]);
            const float4 ev = unpack4(eb2[(size_t)eid * 32 + u32]);
            const float4 vv = unpack4(vb2[(size_t)src * 32 + u32]);
            float s = qv.x * (kv.x + ev.x) + qv.y * (kv.y + ev.y) +
                      qv.z * (kv.z + ev.z) + qv.w * (kv.w + ev.w);
            s += __shfl_xor(s, 1);
            s += __shfl_xor(s, 2);
            s += __shfl_xor(s, 4);
            s += __shfl_xor(s, 8);
            const float p = valid ? __expf(s * SCALE_ATTN) : 0.f;
            denom += p;
            acc.x = fmaf(p, vv.x + ev.x, acc.x);
            acc.y = fmaf(p, vv.y + ev.y, acc.y);
            acc.z = fmaf(p, vv.z + ev.z, acc.z);
            acc.w = fmaf(p, vv.w + ev.w, acc.w);
        }
    }
    acc.x += __shfl_xor(acc.x, 32);
    acc.y += __shfl_xor(acc.y, 32);
    acc.z += __shfl_xor(acc.z, 32);
    acc.w += __shfl_xor(acc.w, 32);
    denom += __shfl_xor(denom, 32);

    if (l < 32) {
        const float inv = 1.f / (denom + 1e-16f);
        float4* o = out4 + (size_t)d * 32 + u32;
        const float4 cur = *o;                    // skip (from k_node v|skip pass)
        *o = make_float4(fmaf(acc.x, inv, cur.x), fmaf(acc.y, inv, cur.y),
                         fmaf(acc.z, inv, cur.z), fmaf(acc.w, inv, cur.w));
    }
}

// ---------------------------------------------------------------------------
extern "C" void kernel_launch(void* const* d_in, const int* in_sizes, int n_in,
                              void* d_out, int out_size, void* d_ws, size_t ws_size,
                              hipStream_t stream)
{
    const float* x   = (const float*)d_in[0];
    const float* lu  = (const float*)d_in[1];
    const int*   ei  = (const int*)d_in[2];
    const float* t   = (const float*)d_in[3];
    const float* msg = (const float*)d_in[4];
    const float* tw  = (const float*)d_in[5];
    const float* tb  = (const float*)d_in[6];
    const float* Wq  = (const float*)d_in[7];
    const float* bq  = (const float*)d_in[8];
    const float* Wk  = (const float*)d_in[9];
    const float* bk  = (const float*)d_in[10];
    const float* Wv  = (const float*)d_in[11];
    const float* bv  = (const float*)d_in[12];
    const float* We  = (const float*)d_in[13];
    const float* Wsk = (const float*)d_in[14];
    const float* bsk = (const float*)d_in[15];

    const int N = in_sizes[1];   // last_update: N elements
    const int E = in_sizes[3];   // t: E elements
    float* out = (float*)d_out;

    char* ws = (char*)d_ws;
    unsigned short* qb = (unsigned short*)ws;  ws += (size_t)N * 128 * sizeof(unsigned short);
    unsigned short* kb = (unsigned short*)ws;  ws += (size_t)N * 128 * sizeof(unsigned short);
    unsigned short* vb = (unsigned short*)ws;  ws += (size_t)N * 128 * sizeof(unsigned short);
    unsigned short* eb = (unsigned short*)ws;  ws += (size_t)E * 128 * sizeof(unsigned short);
    int*   counts  = (int*)ws;   ws += (size_t)N * sizeof(int);
    int*   rowptr  = (int*)ws;   ws += (size_t)N * sizeof(int);
    int*   cursor  = (int*)ws;   ws += (size_t)N * sizeof(int);
    int*   perm    = (int*)ws;   ws += (size_t)E * sizeof(int);
    int*   srcp    = (int*)ws;   ws += (size_t)E * sizeof(int);
    float* relo    = (float*)ws; ws += (size_t)E * sizeof(float);
    int*   partial = (int*)ws;   ws += 512 * sizeof(int);
    int*   baseArr = (int*)ws;   ws += 512 * sizeof(int);

    const int nScan = (N + SCAN_CHUNK - 1) / SCAN_CHUNK;

    hipMemsetAsync(counts, 0, (size_t)N * sizeof(int), stream);

    // CSR build (k_edge only needs relo; k_agg needs perm/srcp/rowptr/counts)
    k_hist<<<(E + 255) / 256, 256, 0, stream>>>(ei, counts, E);
    k_scan_partial<<<nScan, 256, 0, stream>>>(counts, partial, N);
    k_scan_base<<<1, 256, 0, stream>>>(partial, baseArr, nScan);
    k_scan_final<<<nScan, 256, 0, stream>>>(counts, baseArr, rowptr, cursor, N);
    k_fill<<<(E + 255) / 256, 256, 0, stream>>>(ei, t, lu, cursor, perm, srcp, relo, E);

    // node linears: [q|k] then [v|skip->d_out]
    const int nTN = (N + 127) / 128;
    k_node_mfma<<<min(nTN, 512), 512, 0, stream>>>(
        (const float4*)x, Wq, Wk, bq, bk, qb, kb, nullptr, N, nTN);
    k_node_mfma<<<min(nTN, 512), 512, 0, stream>>>(
        (const float4*)x, Wv, Wsk, bv, bsk, vb, nullptr, out, N, nTN);

    // edge GEMM in original order: sequential reads + sequential writes
    const int nTE = (E + 127) / 128;
    k_edge_mfma<<<min(nTE, 1024), 512, 0, stream>>>(
        (const float4*)msg, relo,
        (const float4*)tw, (const float4*)tb, We, eb, E, nTE);

    // fused aggregation (e gathered via perm; no atomics)
    k_agg<<<(N + 3) / 4, 256, 0, stream>>>(
        srcp, perm, rowptr, counts,
        (const uint2*)qb, (const uint2*)kb, (const uint2*)vb, (const uint2*)eb,
        (float4*)out, N);
}